// Round 13
// baseline (50.929 us; speedup 1.0000x reference)
//
#include <hip/hip_runtime.h>
#include <hip/hip_bf16.h>
#include <hip/hip_cooperative_groups.h>
#include <math.h>

namespace cg = cooperative_groups;

#define HH 4
#define DD 64
#define BS 32
#define SSEL 4
#define STRIDE (HH * DD)

typedef __attribute__((ext_vector_type(8))) short bf16x8;
typedef __attribute__((ext_vector_type(4))) float f32x4;

__device__ __forceinline__ float silu_f(float x) { return x / (1.0f + __expf(-x)); }

__device__ __forceinline__ unsigned int pk2bf(float a, float b) {
    union { __hip_bfloat16 h[2]; unsigned int u; } cu;
    cu.h[0] = __float2bfloat16(a);
    cu.h[1] = __float2bfloat16(b);
    return cu.u;
}

// ---------------------------------------------------------------------------
// Cooperative single kernel. Part A: block means once, grid-wide. grid.sync().
// Part B: per-(query-block, head) fused cmp+sel+slc (verified engine).
__global__ __launch_bounds__(512, 2) void nsa_coop(
        const float* __restrict__ q, const float* __restrict__ k,
        const float* __restrict__ v, const float* __restrict__ gc,
        const float* __restrict__ gs, const int* __restrict__ offs,
        float* __restrict__ kc, float* __restrict__ vc,
        int B, int T, float* __restrict__ out) {
    __shared__ float Qf[32][68];
    __shared__ float Kc[16][68];
    __shared__ float Vc[16][64];
    __shared__ float Sc[32][17];
    __shared__ float Ps[32][17];
    __shared__ unsigned char selb[32][16];
    __shared__ unsigned int  Msk[32];
    __shared__ unsigned short Qs[32][64];
    __shared__ __align__(16) char UN[4 * 32 * 68 * 4];   // Pw (ph4) / Op (ph5/6)

    unsigned int (*Pw)[32][20] = (unsigned int (*)[32][20])UN;
    float        (*Op)[32][68] = (float (*)[32][68])UN;

    int tid = threadIdx.x;
    int w = tid >> 6, lane = tid & 63;
    int l15 = lane & 15, g = lane >> 4;
    const float scale = 0.125f;

    // ================= PART A: block means (each computed once) =================
    {
        int tcb = 0;
        #pragma unroll 1
        for (int i = 0; i < B; ++i) tcb += (offs[i + 1] - offs[i] + BS - 1) / BS;
        int totalUnits = tcb * HH * 2;
        int nwg = (int)gridDim.x;
        #pragma unroll 1
        for (int u = w * nwg + (int)blockIdx.x; u < totalUnits; u += 8 * nwg) {
            int ci = u / (HH * 2), rest = u % (HH * 2);
            int h2 = rest >> 1, kind = rest & 1;
            int bb = 0, c0 = 0;
            #pragma unroll 1
            for (;;) {
                int nc = (offs[bb + 1] - offs[bb] + BS - 1) / BS;
                if (ci < c0 + nc) break;
                c0 += nc; ++bb;
            }
            int blk  = ci - c0;
            int off2 = offs[bb];
            int nn   = offs[bb + 1] - off2;
            int rg = lane >> 4, d16 = lane & 15;
            const float* src = kind ? v : k;
            const float4* sp = (const float4*)(src + (size_t)(off2 + blk * BS) * STRIDE
                                               + h2 * DD + d16 * 4);
            int rmax = min(BS, nn - blk * BS);
            float4 acc = {0.f, 0.f, 0.f, 0.f};
            #pragma unroll
            for (int i = 0; i < 8; ++i) {
                int row = rg * 8 + i;
                if (row < rmax) {
                    float4 x = sp[(size_t)row * (STRIDE / 4)];
                    acc.x += x.x; acc.y += x.y; acc.z += x.z; acc.w += x.w;
                }
            }
            #pragma unroll
            for (int m = 16; m <= 32; m <<= 1) {
                acc.x += __shfl_xor(acc.x, m, 64);
                acc.y += __shfl_xor(acc.y, m, 64);
                acc.z += __shfl_xor(acc.z, m, 64);
                acc.w += __shfl_xor(acc.w, m, 64);
            }
            if (rg == 0) {
                float4 r;
                r.x = acc.x * (1.f / BS); r.y = acc.y * (1.f / BS);
                r.z = acc.z * (1.f / BS); r.w = acc.w * (1.f / BS);
                *(float4*)((kind ? vc : kc) + ((size_t)ci * HH + h2) * DD + d16 * 4) = r;
            }
        }
    }
    cg::this_grid().sync();

    // ================= PART B: fused per-(qb, h) =================
    int qbh = blockIdx.x;
    int h   = qbh & (HH - 1);
    int qb  = qbh / HH;

    int b = -1, lb = 0, cum = 0, off = 0, n = 0;
    for (int i = 0; i < B; ++i) {
        int o0 = offs[i], o1 = offs[i + 1];
        int nbi = (o1 - o0 + BS - 1) / BS;
        if (qb < cum + nbi) { b = i; lb = qb - cum; off = o0; n = o1 - o0; break; }
        cum += nbi;
    }
    if (b < 0) return;
    int cbase = cum;
    int t0  = off + lb * BS;
    int nbl = lb + 1;                // <= 16 (seqlen <= 512)

    // ---- phase 0a: stage Q (f32 + bf16 swizzled) ----
    {
        int row = tid >> 4, dg = tid & 15;
        int trow = min(t0 + row, T - 1);
        float4 a = *(const float4*)(q + (size_t)trow * STRIDE + h * DD + dg * 4);
        a.x *= scale; a.y *= scale; a.z *= scale; a.w *= scale;
        *(float4*)&Qf[row][dg * 4] = a;
        uint2 uu = { pk2bf(a.x, a.y), pk2bf(a.z, a.w) };
        *(uint2*)&Qs[row][(((dg >> 1) ^ (row & 7)) * 8) + (dg & 1) * 4] = uu;
    }
    // ---- phase 0b: stage kc/vc tiles (8 KB, L2-hot) ----
    for (int idx = tid; idx < nbl * 16; idx += 512) {
        int row = idx >> 4, dg = idx & 15;
        size_t src = ((size_t)(cbase + row) * HH + h) * DD + dg * 4;
        *(float4*)&Kc[row][dg * 4] = *(const float4*)(kc + src);
        *(float4*)&Vc[row][dg * 4] = *(const float4*)(vc + src);
    }
    __syncthreads();

    // ---- phase 1: cmp scores fp32 (exact) ----
    {
        int qq = tid >> 4, j = tid & 15;
        if (j < nbl) {
            float s = 0.f;
            #pragma unroll
            for (int i = 0; i < 16; ++i) {
                float4 qv = *(float4*)&Qf[qq][i * 4];
                float4 kk = *(float4*)&Kc[j][i * 4];
                s += qv.x * kk.x + qv.y * kk.y + qv.z * kk.z + qv.w * kk.w;
            }
            Sc[qq][j] = s;
        }
    }
    __syncthreads();

    // ---- phase 2: rank -> selection bits + silu ----
    {
        int qq = tid >> 4, j = tid & 15;
        if (j < nbl) {
            float sj = Sc[qq][j];
            int rank = 0;
            for (int i = 0; i < nbl; ++i) {
                float si = Sc[qq][i];
                rank += (si > sj) || (si == sj && i < j);
            }
            selb[qq][j] = (unsigned char)(rank < SSEL);
            Ps[qq][j]   = silu_f(sj);
        } else {
            selb[qq][j] = 0;
        }
    }
    __syncthreads();

    // ---- phase 3: masks + cmp PV + gc gate + store o_cmp ----
    if (tid < 32) {
        unsigned int m = 0;
        #pragma unroll
        for (int j = 0; j < 16; ++j) m |= ((unsigned int)selb[tid][j]) << j;
        Msk[tid] = m;
    }
    {
        int qq = tid >> 4, dg = tid & 15;
        float4 o = {0.f, 0.f, 0.f, 0.f};
        for (int blk = 0; blk < nbl; ++blk) {
            float p = Ps[qq][blk];
            float4 vv = *(float4*)&Vc[blk][dg * 4];
            o.x += p * vv.x; o.y += p * vv.y; o.z += p * vv.z; o.w += p * vv.w;
        }
        if (lb * BS + qq < n) {
            float gv = gc[(size_t)(t0 + qq) * HH + h];
            o.x *= gv; o.y *= gv; o.z *= gv; o.w *= gv;
            *(float4*)(out + (size_t)(t0 + qq) * STRIDE + h * DD + dg * 4) = o;
        }
    }
    __syncthreads();

    // ---- phase 4: slc attention via MFMA (verified engine) ----
    unsigned int Msq[2];
    Msq[0] = Msk[l15];
    Msq[1] = Msk[16 + l15];

    f32x4 oacc[4][2];
    #pragma unroll
    for (int dt = 0; dt < 4; ++dt)
        #pragma unroll
        for (int qt = 0; qt < 2; ++qt)
            oacc[dt][qt] = (f32x4){0.f, 0.f, 0.f, 0.f};

    #pragma unroll 1
    for (int kb = w; kb <= lb; kb += 8) {
        const float* kbase = k + (size_t)(off + kb * BS) * STRIDE + h * DD;
        const float* vbase = v + (size_t)(off + kb * BS) * STRIDE + h * DD;

        float4 kf[2][2][2];
        #pragma unroll
        for (int tt = 0; tt < 2; ++tt)
            #pragma unroll
            for (int ds = 0; ds < 2; ++ds) {
                const float4* p = (const float4*)(kbase + (size_t)(tt * 16 + l15) * STRIDE
                                                  + ds * 32 + g * 8);
                kf[tt][ds][0] = p[0];
                kf[tt][ds][1] = p[1];
            }
        float tv[4][8];
        #pragma unroll
        for (int dt = 0; dt < 4; ++dt)
            #pragma unroll
            for (int j = 0; j < 8; ++j)
                tv[dt][j] = vbase[(size_t)(g * 8 + j) * STRIDE + dt * 16 + l15];

        bf16x8 a1[2][2];
        #pragma unroll
        for (int tt = 0; tt < 2; ++tt)
            #pragma unroll
            for (int ds = 0; ds < 2; ++ds) {
                union { unsigned int u[4]; bf16x8 v8; } cu;
                float4 x = kf[tt][ds][0], y = kf[tt][ds][1];
                cu.u[0] = pk2bf(x.x, x.y); cu.u[1] = pk2bf(x.z, x.w);
                cu.u[2] = pk2bf(y.x, y.y); cu.u[3] = pk2bf(y.z, y.w);
                a1[tt][ds] = cu.v8;
            }
        bf16x8 b1[2][2];
        #pragma unroll
        for (int ds = 0; ds < 2; ++ds)
            #pragma unroll
            for (int tt = 0; tt < 2; ++tt)
                b1[tt][ds] = *(bf16x8*)&Qs[tt * 16 + l15][((g + ds * 4) ^ (l15 & 7)) * 8];

        f32x4 s[2][2];
        #pragma unroll
        for (int kt = 0; kt < 2; ++kt)
            #pragma unroll
            for (int qt = 0; qt < 2; ++qt) {
                s[kt][qt] = (f32x4){0.f, 0.f, 0.f, 0.f};
                s[kt][qt] = __builtin_amdgcn_mfma_f32_16x16x32_bf16(a1[kt][0], b1[qt][0], s[kt][qt], 0, 0, 0);
                s[kt][qt] = __builtin_amdgcn_mfma_f32_16x16x32_bf16(a1[kt][1], b1[qt][1], s[kt][qt], 0, 0, 0);
            }

        #pragma unroll
        for (int kt = 0; kt < 2; ++kt)
            #pragma unroll
            for (int qt = 0; qt < 2; ++qt) {
                bool selbit = (Msq[qt] >> kb) & 1u;
                float pv[4];
                #pragma unroll
                for (int r = 0; r < 4; ++r) {
                    int k_l = kt * 16 + g * 4 + r;
                    int q_l = qt * 16 + l15;
                    bool ok = selbit && (kb < lb || k_l <= q_l);
                    pv[r] = ok ? silu_f(s[kt][qt][r]) : 0.f;
                }
                Pw[w][qt * 16 + l15][kt * 8 + g * 2 + 0] = pk2bf(pv[0], pv[1]);
                Pw[w][qt * 16 + l15][kt * 8 + g * 2 + 1] = pk2bf(pv[2], pv[3]);
            }
        bf16x8 b2[2];
        b2[0] = *(bf16x8*)&Pw[w][l15][g * 4];
        b2[1] = *(bf16x8*)&Pw[w][16 + l15][g * 4];

        bf16x8 a2[4];
        #pragma unroll
        for (int dt = 0; dt < 4; ++dt) {
            union { unsigned int u[4]; bf16x8 v8; } cu;
            cu.u[0] = pk2bf(tv[dt][0], tv[dt][1]);
            cu.u[1] = pk2bf(tv[dt][2], tv[dt][3]);
            cu.u[2] = pk2bf(tv[dt][4], tv[dt][5]);
            cu.u[3] = pk2bf(tv[dt][6], tv[dt][7]);
            a2[dt] = cu.v8;
        }

        #pragma unroll
        for (int dt = 0; dt < 4; ++dt)
            #pragma unroll
            for (int qt = 0; qt < 2; ++qt)
                oacc[dt][qt] = __builtin_amdgcn_mfma_f32_16x16x32_bf16(a2[dt], b2[qt], oacc[dt][qt], 0, 0, 0);
    }
    __syncthreads();   // all waves done with Pw before Op overlays it

    // ---- phase 5: two-step plane accumulation ----
    if (w < 4) {
        #pragma unroll
        for (int dt = 0; dt < 4; ++dt)
            #pragma unroll
            for (int qt = 0; qt < 2; ++qt)
                #pragma unroll
                for (int r = 0; r < 4; ++r)
                    Op[w][qt * 16 + l15][dt * 16 + g * 4 + r] = oacc[dt][qt][r];
    }
    __syncthreads();
    if (w >= 4) {
        #pragma unroll
        for (int dt = 0; dt < 4; ++dt)
            #pragma unroll
            for (int qt = 0; qt < 2; ++qt)
                #pragma unroll
                for (int r = 0; r < 4; ++r)
                    Op[w - 4][qt * 16 + l15][dt * 16 + g * 4 + r] += oacc[dt][qt][r];
    }
    __syncthreads();

    // ---- phase 6: combine planes, gate, store o_slc ----
    {
        int qq = tid >> 4, dg = tid & 15;
        if (lb * BS + qq < n) {
            float gv = gs[(size_t)(t0 + qq) * HH + h];
            float o[4];
            #pragma unroll
            for (int i = 0; i < 4; ++i) {
                int d = dg * 4 + i;
                o[i] = (Op[0][qq][d] + Op[1][qq][d] + Op[2][qq][d] + Op[3][qq][d]) * gv;
            }
            *(float4*)(out + (size_t)T * STRIDE + (size_t)(t0 + qq) * STRIDE + h * DD + dg * 4)
                = (float4){o[0], o[1], o[2], o[3]};
        }
    }
}

// ---------------------------------------------------------------------------
extern "C" void kernel_launch(void* const* d_in, const int* in_sizes, int n_in,
                              void* d_out, int out_size, void* d_ws, size_t ws_size,
                              hipStream_t stream) {
    const float* q    = (const float*)d_in[0];
    const float* k    = (const float*)d_in[1];
    const float* v    = (const float*)d_in[2];
    const float* gc   = (const float*)d_in[3];
    const float* gs   = (const float*)d_in[4];
    const int*   offs = (const int*)d_in[5];   // JAX x64-off: int32 on device

    int B = in_sizes[5] - 1;
    int T = out_size / (2 * STRIDE);
    int nbcap  = (T + BS - 1) / BS;
    int nqbcap = nbcap + B;                    // upper bound on query blocks

    size_t cmp_elems = (size_t)(nbcap + B) * STRIDE;
    float* kc = (float*)d_ws;
    float* vc = kc + cmp_elems;
    float* outp = (float*)d_out;

    int G = nqbcap * HH;                       // 216 WGs <= 256 CUs (co-resident)
    void* kargs[] = { (void*)&q, (void*)&k, (void*)&v, (void*)&gc, (void*)&gs,
                      (void*)&offs, (void*)&kc, (void*)&vc,
                      (void*)&B, (void*)&T, (void*)&outp };
    hipLaunchCooperativeKernel((const void*)nsa_coop, dim3((unsigned)G), dim3(512),
                               kargs, 0, stream);
}

// Round 14
// 17.622 us; speedup vs baseline: 2.8901x; 2.8901x over previous
//
#include <hip/hip_runtime.h>
#include <hip/hip_bf16.h>
#include <math.h>

#define HH 4
#define DD 64
#define BS 32
#define SSEL 4
#define STRIDE (HH * DD)

typedef __attribute__((ext_vector_type(8))) short bf16x8;
typedef __attribute__((ext_vector_type(4))) float f32x4;

__device__ __forceinline__ float silu_f(float x) { return x / (1.0f + __expf(-x)); }

// RNE f32->bf16 pair pack (compiler emits v_cvt_pk_bf16_f32)
__device__ __forceinline__ unsigned int pk2bf(float a, float b) {
    union { __hip_bfloat16 h[2]; unsigned int u; } cu;
    cu.h[0] = __float2bfloat16(a);
    cu.h[1] = __float2bfloat16(b);
    return cu.u;
}

// ---------------------------------------------------------------------------
// Single fused kernel (R11 structure). One WG (8 waves / 512 threads) per
// (query-block, head). Phases 1-3 fused barrier-free via 16-lane shuffles.
__global__ __launch_bounds__(512, 2) void nsa_all(
        const float* __restrict__ q, const float* __restrict__ k,
        const float* __restrict__ v, const float* __restrict__ gc,
        const float* __restrict__ gs, const int* __restrict__ offs,
        int B, int T, float* __restrict__ out) {
    __shared__ float Qf[32][68];                 // f32 scaled q
    __shared__ float Kc[16][68];                 // f32 block-mean K
    __shared__ float Vc[16][64];                 // f32 block-mean V
    __shared__ unsigned int Msk[32];
    __shared__ unsigned short Qs[32][64];        // bf16, chunk-XOR swizzled
    __shared__ __align__(16) char UN[4 * 32 * 68 * 4];   // Pw (ph4) / Op (ph5/6)

    unsigned int (*Pw)[32][20] = (unsigned int (*)[32][20])UN;
    float        (*Op)[32][68] = (float (*)[32][68])UN;

    int qbh = blockIdx.x;
    int h   = qbh & (HH - 1);
    int qb  = qbh / HH;

    int b = -1, lb = 0, cum = 0, off = 0, n = 0;
    for (int i = 0; i < B; ++i) {
        int o0 = offs[i], o1 = offs[i + 1];
        int nbi = (o1 - o0 + BS - 1) / BS;
        if (qb < cum + nbi) { b = i; lb = qb - cum; off = o0; n = o1 - o0; break; }
        cum += nbi;
    }
    if (b < 0) return;
    int t0  = off + lb * BS;
    int nbl = lb + 1;                // <= 16 (seqlen <= 512)
    const float scale = 0.125f;
    int tid = threadIdx.x;
    int w = tid >> 6, lane = tid & 63;
    int l15 = lane & 15, g = lane >> 4;

    // ---- phase 0a: stage Q (f32 + bf16 swizzled) ----
    {
        int row = tid >> 4, dg = tid & 15;
        int trow = min(t0 + row, T - 1);
        float4 a = *(const float4*)(q + (size_t)trow * STRIDE + h * DD + dg * 4);
        a.x *= scale; a.y *= scale; a.z *= scale; a.w *= scale;
        *(float4*)&Qf[row][dg * 4] = a;
        uint2 uu = { pk2bf(a.x, a.y), pk2bf(a.z, a.w) };
        *(uint2*)&Qs[row][(((dg >> 1) ^ (row & 7)) * 8) + (dg & 1) * 4] = uu;
    }

    // ---- phase 0b: in-WG block means, one float4 column per thread ----
    if (tid < nbl * 32) {
        int j = tid >> 5, rest = tid & 31, kind = rest >> 4, d4 = rest & 15;
        const float* base = (kind ? v : k) + (size_t)(off + j * BS) * STRIDE + h * DD + d4 * 4;
        float4 acc = {0.f, 0.f, 0.f, 0.f};
        #pragma unroll
        for (int r = 0; r < BS; ++r) {
            float4 x = *(const float4*)(base + (size_t)r * STRIDE);
            acc.x += x.x; acc.y += x.y; acc.z += x.z; acc.w += x.w;
        }
        acc.x *= (1.f / BS); acc.y *= (1.f / BS); acc.z *= (1.f / BS); acc.w *= (1.f / BS);
        if (kind) *(float4*)&Vc[j][d4 * 4] = acc;
        else      *(float4*)&Kc[j][d4 * 4] = acc;
    }
    __syncthreads();

    // ---- phases 1+2+3 fused (barrier-free within 16-lane groups) ----
    // thread (qq = tid>>4, j = tid&15): score, rank, silu, PV all via shfl.
    {
        int qq = tid >> 4, j = tid & 15;
        int base16 = lane & 48;
        float s = -INFINITY, p = 0.f;
        if (j < nbl) {
            s = 0.f;
            #pragma unroll
            for (int i = 0; i < 16; ++i) {
                float4 qv = *(float4*)&Qf[qq][i * 4];
                float4 kk = *(float4*)&Kc[j][i * 4];
                s += qv.x * kk.x + qv.y * kk.y + qv.z * kk.z + qv.w * kk.w;
            }
            p = silu_f(s);
        }
        // rank among the 16 group scores (strict >, lower idx wins ties)
        int rank = 0;
        #pragma unroll
        for (int i = 0; i < 16; ++i) {
            float si = __shfl(s, base16 | i, 64);
            rank += (si > s) || (si == s && i < j);
        }
        bool sel = (j < nbl) && (rank < SSEL);
        unsigned long long bal = __ballot(sel);
        if (j == 0) Msk[qq] = (unsigned int)((bal >> base16) & 0xFFFFull);

        // cmp PV: thread (qq, dg=j), p broadcast from group lane blk
        float4 o = {0.f, 0.f, 0.f, 0.f};
        for (int blk = 0; blk < nbl; ++blk) {
            float pb = __shfl(p, base16 | blk, 64);
            float4 vv = *(float4*)&Vc[blk][j * 4];
            o.x += pb * vv.x; o.y += pb * vv.y; o.z += pb * vv.z; o.w += pb * vv.w;
        }
        if (lb * BS + qq < n) {
            float gv = gc[(size_t)(t0 + qq) * HH + h];
            o.x *= gv; o.y *= gv; o.z *= gv; o.w *= gv;
            *(float4*)(out + (size_t)(t0 + qq) * STRIDE + h * DD + j * 4) = o;
        }
    }
    __syncthreads();

    // ---- phase 4: slc attention via MFMA; loads at step head, low pressure ----
    unsigned int Msq[2];
    Msq[0] = Msk[l15];
    Msq[1] = Msk[16 + l15];

    f32x4 oacc[4][2];
    #pragma unroll
    for (int dt = 0; dt < 4; ++dt)
        #pragma unroll
        for (int qt = 0; qt < 2; ++qt)
            oacc[dt][qt] = (f32x4){0.f, 0.f, 0.f, 0.f};

    #pragma unroll 1
    for (int kb = w; kb <= lb; kb += 8) {
        const float* kbase = k + (size_t)(off + kb * BS) * STRIDE + h * DD;
        const float* vbase = v + (size_t)(off + kb * BS) * STRIDE + h * DD;

        // V^T gather first (32 scalar L2 loads -> overlap with K loads below)
        float tv[4][8];
        #pragma unroll
        for (int dt = 0; dt < 4; ++dt)
            #pragma unroll
            for (int j = 0; j < 8; ++j)
                tv[dt][j] = vbase[(size_t)(g * 8 + j) * STRIDE + dt * 16 + l15];

        // K fragments direct from global: a1[tt][ds] = K[tt*16+l15][ds*32+g*8 ..+7]
        float4 kf[2][2][2];
        #pragma unroll
        for (int tt = 0; tt < 2; ++tt)
            #pragma unroll
            for (int ds = 0; ds < 2; ++ds) {
                const float4* p = (const float4*)(kbase + (size_t)(tt * 16 + l15) * STRIDE
                                                  + ds * 32 + g * 8);
                kf[tt][ds][0] = p[0];
                kf[tt][ds][1] = p[1];
            }

        bf16x8 a1[2][2];
        #pragma unroll
        for (int tt = 0; tt < 2; ++tt)
            #pragma unroll
            for (int ds = 0; ds < 2; ++ds) {
                union { unsigned int u[4]; bf16x8 v8; } cu;
                float4 x = kf[tt][ds][0], y = kf[tt][ds][1];
                cu.u[0] = pk2bf(x.x, x.y); cu.u[1] = pk2bf(x.z, x.w);
                cu.u[2] = pk2bf(y.x, y.y); cu.u[3] = pk2bf(y.z, y.w);
                a1[tt][ds] = cu.v8;
            }
        bf16x8 b1[2][2];
        #pragma unroll
        for (int ds = 0; ds < 2; ++ds)
            #pragma unroll
            for (int tt = 0; tt < 2; ++tt)
                b1[tt][ds] = *(bf16x8*)&Qs[tt * 16 + l15][((g + ds * 4) ^ (l15 & 7)) * 8];

        f32x4 s[2][2];
        #pragma unroll
        for (int kt = 0; kt < 2; ++kt)
            #pragma unroll
            for (int qt = 0; qt < 2; ++qt) {
                s[kt][qt] = (f32x4){0.f, 0.f, 0.f, 0.f};
                s[kt][qt] = __builtin_amdgcn_mfma_f32_16x16x32_bf16(a1[kt][0], b1[qt][0], s[kt][qt], 0, 0, 0);
                s[kt][qt] = __builtin_amdgcn_mfma_f32_16x16x32_bf16(a1[kt][1], b1[qt][1], s[kt][qt], 0, 0, 0);
            }

        // mask + silu + pack P (bf16) via wave-private LDS (layout shuffle)
        #pragma unroll
        for (int kt = 0; kt < 2; ++kt)
            #pragma unroll
            for (int qt = 0; qt < 2; ++qt) {
                bool selbit = (Msq[qt] >> kb) & 1u;
                float pv[4];
                #pragma unroll
                for (int r = 0; r < 4; ++r) {
                    int k_l = kt * 16 + g * 4 + r;
                    int q_l = qt * 16 + l15;
                    bool ok = selbit && (kb < lb || k_l <= q_l);
                    pv[r] = ok ? silu_f(s[kt][qt][r]) : 0.f;
                }
                Pw[w][qt * 16 + l15][kt * 8 + g * 2 + 0] = pk2bf(pv[0], pv[1]);
                Pw[w][qt * 16 + l15][kt * 8 + g * 2 + 1] = pk2bf(pv[2], pv[3]);
            }
        bf16x8 b2[2];
        b2[0] = *(bf16x8*)&Pw[w][l15][g * 4];
        b2[1] = *(bf16x8*)&Pw[w][16 + l15][g * 4];

        bf16x8 a2[4];
        #pragma unroll
        for (int dt = 0; dt < 4; ++dt) {
            union { unsigned int u[4]; bf16x8 v8; } cu;
            cu.u[0] = pk2bf(tv[dt][0], tv[dt][1]);
            cu.u[1] = pk2bf(tv[dt][2], tv[dt][3]);
            cu.u[2] = pk2bf(tv[dt][4], tv[dt][5]);
            cu.u[3] = pk2bf(tv[dt][6], tv[dt][7]);
            a2[dt] = cu.v8;
        }

        #pragma unroll
        for (int dt = 0; dt < 4; ++dt)
            #pragma unroll
            for (int qt = 0; qt < 2; ++qt)
                oacc[dt][qt] = __builtin_amdgcn_mfma_f32_16x16x32_bf16(a2[dt], b2[qt], oacc[dt][qt], 0, 0, 0);
    }
    __syncthreads();   // all waves done with Pw before Op overlays it

    // ---- phase 5: two-step plane accumulation ----
    if (w < 4) {
        #pragma unroll
        for (int dt = 0; dt < 4; ++dt)
            #pragma unroll
            for (int qt = 0; qt < 2; ++qt)
                #pragma unroll
                for (int r = 0; r < 4; ++r)
                    Op[w][qt * 16 + l15][dt * 16 + g * 4 + r] = oacc[dt][qt][r];
    }
    __syncthreads();
    if (w >= 4) {
        #pragma unroll
        for (int dt = 0; dt < 4; ++dt)
            #pragma unroll
            for (int qt = 0; qt < 2; ++qt)
                #pragma unroll
                for (int r = 0; r < 4; ++r)
                    Op[w - 4][qt * 16 + l15][dt * 16 + g * 4 + r] += oacc[dt][qt][r];
    }
    __syncthreads();

    // ---- phase 6: combine planes, gate, store o_slc ----
    {
        int qq = tid >> 4, dg = tid & 15;
        if (lb * BS + qq < n) {
            float gv = gs[(size_t)(t0 + qq) * HH + h];
            float o[4];
            #pragma unroll
            for (int i = 0; i < 4; ++i) {
                int d = dg * 4 + i;
                o[i] = (Op[0][qq][d] + Op[1][qq][d] + Op[2][qq][d] + Op[3][qq][d]) * gv;
            }
            *(float4*)(out + (size_t)T * STRIDE + (size_t)(t0 + qq) * STRIDE + h * DD + dg * 4)
                = (float4){o[0], o[1], o[2], o[3]};
        }
    }
}

// ---------------------------------------------------------------------------
extern "C" void kernel_launch(void* const* d_in, const int* in_sizes, int n_in,
                              void* d_out, int out_size, void* d_ws, size_t ws_size,
                              hipStream_t stream) {
    const float* q    = (const float*)d_in[0];
    const float* k    = (const float*)d_in[1];
    const float* v    = (const float*)d_in[2];
    const float* gc   = (const float*)d_in[3];
    const float* gs   = (const float*)d_in[4];
    const int*   offs = (const int*)d_in[5];   // JAX x64-off: int32 on device

    int B = in_sizes[5] - 1;
    int T = out_size / (2 * STRIDE);
    int nbcap  = (T + BS - 1) / BS;
    int nqbcap = nbcap + B;                    // upper bound on query blocks

    nsa_all<<<dim3((unsigned)(nqbcap * HH)), dim3(512), 0, stream>>>(
        q, k, v, gc, gs, offs, B, T, (float*)d_out);
}